// Round 1
// baseline (669.923 us; speedup 1.0000x reference)
//
#include <hip/hip_runtime.h>
#include <hip/hip_bf16.h>
#include <stdint.h>

// Problem constants
#define TT     48000   // T
#define TK     120     // samples per chunk (T/K)
#define NCIN   128
#define NCOUT  128
#define NKS    3
#define NA     384     // CIN*KS
#define NZ     64
#define NH     32
#define NB     4
#define NK     400
#define NCHUNK 1600    // NB*NK
#define MW     49152   // CIN*COUT*KS rows of w2

static __device__ __forceinline__ float bf2f(uint32_t u16) {
    uint32_t x = u16 << 16;
    float f;
    __builtin_memcpy(&f, &x, 4);
    return f;
}
static __device__ __forceinline__ uint32_t f2bf(float f) {
    uint32_t x;
    __builtin_memcpy(&x, &f, 4);
    // round-to-nearest-even
    return (x + 0x7fffu + ((x >> 16) & 1u)) >> 16;
}

// ---------------------------------------------------------------------------
// k1: per-chunk MLP hidden states (weight model) + full bias vector.
//   Hws[chunk][32]   = relu(w1 @ z[b,:,k] + b1)
//   biasws[chunk][128] = bw2 @ relu(bw1 @ z + bb1) + bb2
// ---------------------------------------------------------------------------
__global__ __launch_bounds__(64) void k1_hidden(
    const float* __restrict__ z,
    const float* __restrict__ w1, const float* __restrict__ b1,
    const float* __restrict__ bw1, const float* __restrict__ bb1,
    const float* __restrict__ bw2, const float* __restrict__ bb2,
    float* __restrict__ Hws, float* __restrict__ biasws) {
    int chunk = blockIdx.x;            // b*400 + k
    int b = chunk / NK;
    int k = chunk - b * NK;
    int tid = threadIdx.x;

    __shared__ float zv[NZ];
    __shared__ float hbs[NH];

    zv[tid] = z[((size_t)b * NZ + tid) * NK + k];
    __syncthreads();

    if (tid < NH) {
        float s = b1[tid];
#pragma unroll
        for (int i = 0; i < NZ; ++i) s = fmaf(w1[tid * NZ + i], zv[i], s);
        Hws[(size_t)chunk * NH + tid] = fmaxf(s, 0.f);
    } else {
        int j = tid - NH;
        float s = bb1[j];
#pragma unroll
        for (int i = 0; i < NZ; ++i) s = fmaf(bw1[j * NZ + i], zv[i], s);
        hbs[j] = fmaxf(s, 0.f);
    }
    __syncthreads();

#pragma unroll
    for (int r = 0; r < 2; ++r) {
        int c = r * 64 + tid;
        float s = bb2[c];
#pragma unroll
        for (int j = 0; j < NH; ++j) s = fmaf(bw2[c * NH + j], hbs[j], s);
        biasws[(size_t)chunk * NCOUT + c] = s;
    }
}

// ---------------------------------------------------------------------------
// k2: weight materialization. W_all[chunk_local][m] (bf16), m = a*128 + c.
// GEMM view: [49152 x nchunk] = w2[49152 x 32] @ H[32 x nchunk], K=32.
// One lane per chunk => w2 row index is wave-uniform => SGPR loads (K$),
// H lives in VGPRs. Results transposed through LDS for coalesced stores.
// ---------------------------------------------------------------------------
__global__ __launch_bounds__(256) void k2_wgen(
    const float* __restrict__ Hws,
    const float* __restrict__ w2, const float* __restrict__ b2,
    uint16_t* __restrict__ Wall, int chunk0, int nchunk) {
    int tid = threadIdx.x;
    int m0 = blockIdx.x * 32;
    int cl = blockIdx.y * 256 + tid;                 // local chunk
    int cidx = chunk0 + ((cl < nchunk) ? cl : 0);    // clamped global chunk

    float h[NH];
#pragma unroll
    for (int r = 0; r < 8; ++r)
        *(float4*)&h[r * 4] = *(const float4*)(Hws + (size_t)cidx * NH + r * 4);

    float acc[32];
#pragma unroll
    for (int mt = 0; mt < 32; ++mt) {
        int m = m0 + mt;                              // wave-uniform
        const float* w2r = w2 + (size_t)m * NH;
        float s = b2[m];
#pragma unroll
        for (int j = 0; j < NH; ++j) s = fmaf(w2r[j], h[j], s);
        acc[mt] = s;
    }

    // transpose via LDS (stride 33 -> conflict-free column writes)
    __shared__ float Tile[256][33];
#pragma unroll
    for (int mt = 0; mt < 32; ++mt) Tile[tid][mt] = acc[mt];
    __syncthreads();

#pragma unroll
    for (int it = 0; it < 8; ++it) {
        int idx = it * 256 + tid;   // 0..2047
        int rl = idx >> 3;          // local chunk row 0..255
        int mq = idx & 7;           // m quad 0..7
        int c2 = blockIdx.y * 256 + rl;
        if (c2 < nchunk) {
            float v0 = Tile[rl][mq * 4 + 0];
            float v1 = Tile[rl][mq * 4 + 1];
            float v2 = Tile[rl][mq * 4 + 2];
            float v3 = Tile[rl][mq * 4 + 3];
            uint32_t p0 = f2bf(v0) | (f2bf(v1) << 16);
            uint32_t p1 = f2bf(v2) | (f2bf(v3) << 16);
            *(uint2*)(Wall + (size_t)c2 * MW + m0 + mq * 4) = make_uint2(p0, p1);
        }
    }
}

// ---------------------------------------------------------------------------
// k3: per-chunk conv GEMM. One block per chunk, 256 threads.
// Block computes y[128t x 128c] (t 120..127 masked). Thread = 8t x 8c, split
// as {q*4, 64+q*4} in both t and c so all ds_read_b128 alias only 2-way
// (free). A staged per 32-wide a-tile (a = tap*128 + cin), W from bf16.
// ---------------------------------------------------------------------------
__global__ __launch_bounds__(256) void k3_conv(
    const float* __restrict__ x,
    const uint16_t* __restrict__ Wall,
    const float* __restrict__ biasws,
    float* __restrict__ out, int chunk0) {
    int cl = blockIdx.x;                 // local chunk (batch-relative)
    int chunk = chunk0 + cl;
    int b = chunk / NK;
    int k = chunk - b * NK;
    int kbase = k * TK;
    int tid = threadIdx.x;
    int cq = tid & 15;                   // c group
    int tq = tid >> 4;                   // t group (0..15)

    __shared__ float As[32][128];        // [a_local][t]
    __shared__ float Ws[32][128];        // [a_local][c]

    float acc[8][8];
#pragma unroll
    for (int i = 0; i < 8; ++i)
#pragma unroll
        for (int j = 0; j < 8; ++j) acc[i][j] = 0.f;

    const float* xb = x + (size_t)b * NCIN * TT;
    const uint16_t* wsrc_base = Wall + (size_t)cl * MW;

    for (int at = 0; at < 12; ++at) {
        int a0 = at * 32;
        // ---- stage A tile: 32 rows x 128 t, coalesced (lane = t) ----
        {
            int t = tid & 127;
            int ai0 = tid >> 7;          // 0..1
#pragma unroll
            for (int r = 0; r < 16; ++r) {
                int ai = r * 2 + ai0;
                int a = a0 + ai;
                int cin = a & 127;
                int tap = a >> 7;
                int g = kbase + t - tap; // global sample index (causal shift)
                float v = 0.f;
                if (g >= 0 && g < TT) v = xb[(size_t)cin * TT + g];
                As[ai][t] = v;
            }
        }
        // ---- stage W tile: 32 rows x 128 c from bf16 ----
        {
            const uint16_t* wsrc = wsrc_base + a0 * NCOUT;
#pragma unroll
            for (int r = 0; r < 2; ++r) {
                int f = r * 2048 + tid * 8;
                uint4 raw = *(const uint4*)(wsrc + f);
                float* dst = &Ws[0][0] + f;
                float4 lo, hi;
                lo.x = bf2f(raw.x & 0xffffu); lo.y = bf2f(raw.x >> 16);
                lo.z = bf2f(raw.y & 0xffffu); lo.w = bf2f(raw.y >> 16);
                hi.x = bf2f(raw.z & 0xffffu); hi.y = bf2f(raw.z >> 16);
                hi.z = bf2f(raw.w & 0xffffu); hi.w = bf2f(raw.w >> 16);
                *(float4*)dst = lo;
                *(float4*)(dst + 4) = hi;
            }
        }
        __syncthreads();
        // ---- compute ----
#pragma unroll
        for (int ai = 0; ai < 32; ++ai) {
            float av[8], wv[8];
            *(float4*)&av[0] = *(const float4*)&As[ai][tq * 4];
            *(float4*)&av[4] = *(const float4*)&As[ai][64 + tq * 4];
            *(float4*)&wv[0] = *(const float4*)&Ws[ai][cq * 4];
            *(float4*)&wv[4] = *(const float4*)&Ws[ai][64 + cq * 4];
#pragma unroll
            for (int i = 0; i < 8; ++i)
#pragma unroll
                for (int j = 0; j < 8; ++j)
                    acc[i][j] = fmaf(av[i], wv[j], acc[i][j]);
        }
        __syncthreads();
    }

    // ---- epilogue: +bias, store fp32 [B][COUT][T] ----
    float bv[8];
    *(float4*)&bv[0] = *(const float4*)(biasws + (size_t)chunk * NCOUT + cq * 4);
    *(float4*)&bv[4] = *(const float4*)(biasws + (size_t)chunk * NCOUT + 64 + cq * 4);
#pragma unroll
    for (int j = 0; j < 8; ++j) {
        int c = (j < 4) ? (cq * 4 + j) : (64 + cq * 4 + (j - 4));
        float* o = out + ((size_t)b * NCOUT + c) * TT + kbase;
        // t run 0: t = tq*4 .. +3  (always < 120)
        *(float4*)(o + tq * 4) = make_float4(acc[0][j] + bv[j], acc[1][j] + bv[j],
                                             acc[2][j] + bv[j], acc[3][j] + bv[j]);
        // t run 1: t = 64 + tq*4 .. +3  (valid iff tq < 14)
        if (tq < 14)
            *(float4*)(o + 64 + tq * 4) = make_float4(acc[4][j] + bv[j], acc[5][j] + bv[j],
                                                      acc[6][j] + bv[j], acc[7][j] + bv[j]);
    }
}

// ---------------------------------------------------------------------------
// launch
// ---------------------------------------------------------------------------
extern "C" void kernel_launch(void* const* d_in, const int* in_sizes, int n_in,
                              void* d_out, int out_size, void* d_ws, size_t ws_size,
                              hipStream_t stream) {
    const float* x   = (const float*)d_in[0];
    const float* z   = (const float*)d_in[1];
    const float* w1  = (const float*)d_in[2];
    const float* b1  = (const float*)d_in[3];
    const float* w2  = (const float*)d_in[4];
    const float* b2  = (const float*)d_in[5];
    const float* bw1 = (const float*)d_in[6];
    const float* bb1 = (const float*)d_in[7];
    const float* bw2 = (const float*)d_in[8];
    const float* bb2 = (const float*)d_in[9];
    float* out = (float*)d_out;

    // ws layout: Hws [1600*32 f32] | biasws [1600*128 f32] | Wall [batch*49152 bf16]
    char* ws = (char*)d_ws;
    float* Hws = (float*)ws;
    float* biasws = (float*)(ws + (size_t)NCHUNK * NH * 4);              // +204800
    const size_t wall_off = (size_t)NCHUNK * NH * 4 + (size_t)NCHUNK * NCOUT * 4; // 1024000
    uint16_t* Wall = (uint16_t*)(ws + wall_off);

    // batch chunks through the remaining ws (full 1600 needs ~157.3 MB)
    size_t avail = (ws_size > wall_off) ? (ws_size - wall_off) : 0;
    int batch = (int)(avail / ((size_t)MW * 2));
    if (batch > NCHUNK) batch = NCHUNK;
    if (batch < 1) batch = 1;

    k1_hidden<<<NCHUNK, 64, 0, stream>>>(z, w1, b1, bw1, bb1, bw2, bb2, Hws, biasws);

    for (int c0 = 0; c0 < NCHUNK; c0 += batch) {
        int nc = NCHUNK - c0;
        if (nc > batch) nc = batch;
        dim3 g2(MW / 32, (nc + 255) / 256, 1);
        k2_wgen<<<g2, 256, 0, stream>>>(Hws, w2, b2, Wall, c0, nc);
        k3_conv<<<nc, 256, 0, stream>>>(x, Wall, biasws, out, c0);
    }
}

// Round 2
// 370.449 us; speedup vs baseline: 1.8084x; 1.8084x over previous
//
#include <hip/hip_runtime.h>
#include <stdint.h>

// Problem constants
#define TT     48000   // T
#define TK     120     // samples per chunk (T/K)
#define NC     128     // CIN == COUT
#define NA     384     // CIN*KS
#define NZ     64
#define NH     32
#define NK     400
#define NCHUNK 1600    // B*K
#define MW     49152   // CIN*COUT*KS
#define XROWS  48002   // T + 2 zero prefix rows (causal taps)

typedef float f32x4 __attribute__((ext_vector_type(4)));
typedef __bf16 bf16x8 __attribute__((ext_vector_type(8)));

static __device__ __forceinline__ uint16_t f2bf(float f) {
    uint32_t x; __builtin_memcpy(&x, &f, 4);
    return (uint16_t)((x + 0x7fffu + ((x >> 16) & 1u)) >> 16);
}
static __device__ __forceinline__ uint32_t pk2(uint16_t lo, uint16_t hi) {
    return (uint32_t)lo | ((uint32_t)hi << 16);
}

// ---------------------------------------------------------------------------
// k0w: permute+convert w2 -> w2p bf16 [m'][32], m' = c*384 + a  (m = a*128+c)
//      and b2 -> b2p f32 [m'].
// ---------------------------------------------------------------------------
__global__ __launch_bounds__(256) void k0w(
    const float* __restrict__ w2, const float* __restrict__ b2,
    uint16_t* __restrict__ w2p, float* __restrict__ b2p) {
    int m = blockIdx.x * 256 + threadIdx.x;   // 0..49151
    int a = m >> 7, c = m & 127;
    int mp = c * NA + a;
    const float* src = w2 + (size_t)m * NH;
    uint16_t* dst = w2p + (size_t)mp * NH;
#pragma unroll
    for (int i = 0; i < NH; i += 8) {
        float4 v0 = *(const float4*)(src + i);
        float4 v1 = *(const float4*)(src + i + 4);
        uint4 o;
        o.x = pk2(f2bf(v0.x), f2bf(v0.y));
        o.y = pk2(f2bf(v0.z), f2bf(v0.w));
        o.z = pk2(f2bf(v1.x), f2bf(v1.y));
        o.w = pk2(f2bf(v1.z), f2bf(v1.w));
        *(uint4*)(dst + i) = o;
    }
    b2p[mp] = b2[m];
}

// ---------------------------------------------------------------------------
// k0x: transpose x[b][cin][t] f32 -> Xt[b][t+2][cin] bf16 (2 zero prefix rows)
// tile: 128 t x 64 cin per block
// ---------------------------------------------------------------------------
__global__ __launch_bounds__(256) void k0x(
    const float* __restrict__ x, uint16_t* __restrict__ Xt) {
    int t0 = blockIdx.x * 128, cin0 = blockIdx.y * 64, b = blockIdx.z;
    int tid = threadIdx.x;
    __shared__ __align__(16) uint16_t Lt[128][72];   // pad row to 72 (144B)
    const float* xb = x + ((size_t)b * NC + cin0) * TT + t0;
    int cg = (tid & 7) * 8;    // local cin base (0..56)
    int tq = (tid >> 3) * 4;   // local t base   (0..124)
    uint16_t vb[4][8];         // [t][cin]
#pragma unroll
    for (int i = 0; i < 8; ++i) {
        float4 v = *(const float4*)(xb + (size_t)(cg + i) * TT + tq);
        vb[0][i] = f2bf(v.x); vb[1][i] = f2bf(v.y);
        vb[2][i] = f2bf(v.z); vb[3][i] = f2bf(v.w);
    }
#pragma unroll
    for (int j = 0; j < 4; ++j) {
        uint4 o; __builtin_memcpy(&o, vb[j], 16);
        *(uint4*)&Lt[tq + j][cg] = o;
    }
    __syncthreads();
    uint16_t* XtB = Xt + (size_t)b * XROWS * NC;
#pragma unroll
    for (int r = 0; r < 4; ++r) {
        int s = r * 256 + tid;
        int t = s >> 3, cc = s & 7;
        uint4 o = *(uint4*)&Lt[t][cc * 8];
        *(uint4*)(XtB + (size_t)(t0 + t + 2) * NC + cin0 + cc * 8) = o;
    }
    if (blockIdx.x == 0 && blockIdx.y == 0 && tid < 32)
        *(uint4*)(XtB + tid * 8) = make_uint4(0, 0, 0, 0);  // zero rows -2,-1
}

// ---------------------------------------------------------------------------
// k1: per-chunk MLP hidden states (bf16) + bias vector (f32)
// ---------------------------------------------------------------------------
__global__ __launch_bounds__(64) void k1_hidden(
    const float* __restrict__ z,
    const float* __restrict__ w1, const float* __restrict__ b1,
    const float* __restrict__ bw1, const float* __restrict__ bb1,
    const float* __restrict__ bw2, const float* __restrict__ bb2,
    uint16_t* __restrict__ Hb, float* __restrict__ biasws) {
    int chunk = blockIdx.x;
    int b = chunk / NK;
    int k = chunk - b * NK;
    int tid = threadIdx.x;

    __shared__ float zv[NZ];
    __shared__ float hbs[NH];

    zv[tid] = z[((size_t)b * NZ + tid) * NK + k];
    __syncthreads();

    if (tid < NH) {
        float s = b1[tid];
#pragma unroll
        for (int i = 0; i < NZ; ++i) s = fmaf(w1[tid * NZ + i], zv[i], s);
        Hb[(size_t)chunk * NH + tid] = f2bf(fmaxf(s, 0.f));
    } else {
        int j = tid - NH;
        float s = bb1[j];
#pragma unroll
        for (int i = 0; i < NZ; ++i) s = fmaf(bw1[j * NZ + i], zv[i], s);
        hbs[j] = fmaxf(s, 0.f);
    }
    __syncthreads();

#pragma unroll
    for (int r = 0; r < 2; ++r) {
        int c = r * 64 + tid;
        float s = bb2[c];
#pragma unroll
        for (int j = 0; j < NH; ++j) s = fmaf(bw2[c * NH + j], hbs[j], s);
        biasws[(size_t)chunk * NC + c] = s;
    }
}

// ---------------------------------------------------------------------------
// k2: MFMA weight materialization. Wt[cl][m'] bf16, m' = c*384+a.
// D[16 m' x 16 chunk] per tile, K=32 = one mfma. No LDS.
// ---------------------------------------------------------------------------
__global__ __launch_bounds__(256) void k2_wgen(
    const uint16_t* __restrict__ w2p, const float* __restrict__ b2p,
    const uint16_t* __restrict__ Hb, uint16_t* __restrict__ Wt,
    int chunk0, int nchunk) {
    int tid = threadIdx.x, lane = tid & 63, w = tid >> 6;
    int quad = lane >> 4, li = lane & 15;
    int clocal = blockIdx.y * 16 + li;
    int cl = clocal < nchunk ? clocal : (nchunk - 1);
    bf16x8 bfrag = *(const bf16x8*)(Hb + (size_t)(chunk0 + cl) * NH + quad * 8);
    int mbase = blockIdx.x * 1024 + w * 256;
    uint16_t* wout = Wt + (size_t)clocal * MW;
#pragma unroll
    for (int tile = 0; tile < 16; ++tile) {
        int mb = mbase + tile * 16;
        bf16x8 afrag = *(const bf16x8*)(w2p + (size_t)(mb + li) * NH + quad * 8);
        f32x4 acc = {0.f, 0.f, 0.f, 0.f};
        acc = __builtin_amdgcn_mfma_f32_16x16x32_bf16(afrag, bfrag, acc, 0, 0, 0);
        float4 bias = *(const float4*)(b2p + mb + quad * 4);
        if (clocal < nchunk) {
            uint16_t p[4] = { f2bf(acc[0] + bias.x), f2bf(acc[1] + bias.y),
                              f2bf(acc[2] + bias.z), f2bf(acc[3] + bias.w) };
            uint64_t pv; __builtin_memcpy(&pv, p, 8);
            *(uint64_t*)(wout + mb + quad * 4) = pv;
        }
    }
}

// ---------------------------------------------------------------------------
// k3: per-chunk conv GEMM via MFMA. Block = chunk, 4 waves, each 64t x 64c.
// A/B staged with global_load_lds(16B) into [kc][row] layout
// (conflict-free ds_read_b128: bank group = 4*(lane&7)).
// ---------------------------------------------------------------------------
__global__ __launch_bounds__(256) void k3_conv(
    const uint16_t* __restrict__ Xt, const uint16_t* __restrict__ Wt,
    const float* __restrict__ biasws, float* __restrict__ out, int chunk0) {
    int cl = blockIdx.x, chunk = chunk0 + cl;
    int b = chunk / NK, k = chunk - b * NK;
    int kbase = k * TK;
    int tid = threadIdx.x, lane = tid & 63, w = tid >> 6;
    int quad = lane >> 4, li = lane & 15;
    int tblk = (w & 1) * 64, cblk = (w >> 1) * 64;

    __shared__ __align__(16) char smem[32768];
    char* As = smem;            // 8 kc x 128 t x 16B
    char* Ws = smem + 16384;    // 8 kc x 128 c x 16B
    const uint16_t* XtB = Xt + (size_t)b * XROWS * NC;
    const uint16_t* WtC = Wt + (size_t)cl * MW;

    f32x4 acc[4][4];
#pragma unroll
    for (int i = 0; i < 4; ++i)
#pragma unroll
        for (int j = 0; j < 4; ++j) acc[i][j] = (f32x4){0.f, 0.f, 0.f, 0.f};

#pragma unroll
    for (int dk = 0; dk < 6; ++dk) {
        int a0 = dk * 64, tap = a0 >> 7, cin0 = a0 & 127;
        // stage A: wave w covers kc = 2w..2w+1, two 64-row halves each
#pragma unroll
        for (int i = 0; i < 4; ++i) {
            int kc = 2 * w + (i >> 1), half = i & 1;
            int t = half * 64 + lane;
            const uint16_t* g = XtB + (size_t)(kbase + t - tap + 2) * NC + cin0 + kc * 8;
            __builtin_amdgcn_global_load_lds(
                (__attribute__((address_space(1))) void*)g,
                (__attribute__((address_space(3))) void*)(As + kc * 2048 + half * 1024),
                16, 0, 0);
        }
#pragma unroll
        for (int i = 0; i < 4; ++i) {
            int kc = 2 * w + (i >> 1), half = i & 1;
            int c = half * 64 + lane;
            const uint16_t* g = WtC + (size_t)c * NA + a0 + kc * 8;
            __builtin_amdgcn_global_load_lds(
                (__attribute__((address_space(1))) void*)g,
                (__attribute__((address_space(3))) void*)(Ws + kc * 2048 + half * 1024),
                16, 0, 0);
        }
        __syncthreads();
#pragma unroll
        for (int s = 0; s < 2; ++s) {
            bf16x8 af[4], bfr[4];
#pragma unroll
            for (int tt = 0; tt < 4; ++tt)
                af[tt] = *(const bf16x8*)(As + (s * 4 + quad) * 2048 + (tblk + tt * 16 + li) * 16);
#pragma unroll
            for (int ct = 0; ct < 4; ++ct)
                bfr[ct] = *(const bf16x8*)(Ws + (s * 4 + quad) * 2048 + (cblk + ct * 16 + li) * 16);
#pragma unroll
            for (int tt = 0; tt < 4; ++tt)
#pragma unroll
                for (int ct = 0; ct < 4; ++ct)
                    acc[tt][ct] = __builtin_amdgcn_mfma_f32_16x16x32_bf16(
                        af[tt], bfr[ct], acc[tt][ct], 0, 0, 0);
        }
        __syncthreads();
    }

    // epilogue: D col = c = lane&15 (+tile), row = t = quad*4+reg (+tile)
#pragma unroll
    for (int ct = 0; ct < 4; ++ct) {
        int c = cblk + ct * 16 + li;
        float bias = biasws[(size_t)chunk * NC + c];
        float* ob = out + ((size_t)b * NC + c) * TT + kbase;
#pragma unroll
        for (int tt = 0; tt < 4; ++tt) {
            int t0v = tblk + tt * 16 + quad * 4;
            if (t0v < TK) {
                f32x4 v = acc[tt][ct];
                *(float4*)(ob + t0v) = make_float4(v[0] + bias, v[1] + bias,
                                                   v[2] + bias, v[3] + bias);
            }
        }
    }
}

// ---------------------------------------------------------------------------
// launch
// ---------------------------------------------------------------------------
extern "C" void kernel_launch(void* const* d_in, const int* in_sizes, int n_in,
                              void* d_out, int out_size, void* d_ws, size_t ws_size,
                              hipStream_t stream) {
    const float* x   = (const float*)d_in[0];
    const float* z   = (const float*)d_in[1];
    const float* w1  = (const float*)d_in[2];
    const float* b1  = (const float*)d_in[3];
    const float* w2  = (const float*)d_in[4];
    const float* b2  = (const float*)d_in[5];
    const float* bw1 = (const float*)d_in[6];
    const float* bb1 = (const float*)d_in[7];
    const float* bw2 = (const float*)d_in[8];
    const float* bb2 = (const float*)d_in[9];
    float* out = (float*)d_out;

    // ws layout (all 256-aligned):
    char* ws = (char*)d_ws;
    uint16_t* Hb     = (uint16_t*)(ws);                 //   102,400 B
    float*    biasws = (float*)(ws + 102400);           //   819,200 B
    uint16_t* w2p    = (uint16_t*)(ws + 921600);        // 3,145,728 B
    float*    b2p    = (float*)(ws + 4067328);          //   196,608 B
    uint16_t* Xt     = (uint16_t*)(ws + 4263936);       // 49,158,144 B (incl. tail pad)
    const size_t wt_off = 53422080;
    uint16_t* Wt     = (uint16_t*)(ws + wt_off);        // up to 157,286,400 B

    size_t avail = (ws_size > wt_off) ? (ws_size - wt_off) : 0;
    int batch = (int)(avail / ((size_t)MW * 2));
    if (batch > NCHUNK) batch = NCHUNK;
    if (batch < 1) batch = 1;

    k0w<<<MW / 256, 256, 0, stream>>>(w2, b2, w2p, b2p);
    k0x<<<dim3(TT / 128, 2, 4), 256, 0, stream>>>(x, Xt);
    k1_hidden<<<NCHUNK, 64, 0, stream>>>(z, w1, b1, bw1, bb1, bw2, bb2, Hb, biasws);

    for (int c0 = 0; c0 < NCHUNK; c0 += batch) {
        int nc = NCHUNK - c0;
        if (nc > batch) nc = batch;
        dim3 g2(MW / 1024, (nc + 15) / 16, 1);
        k2_wgen<<<g2, 256, 0, stream>>>(w2p, b2p, Hb, Wt, c0, nc);
        k3_conv<<<nc, 256, 0, stream>>>(Xt, Wt, biasws, out, c0);
    }
}

// Round 3
// 323.526 us; speedup vs baseline: 2.0707x; 1.1450x over previous
//
#include <hip/hip_runtime.h>
#include <stdint.h>

// Problem constants
#define TT     48000   // T
#define TK     120     // samples per chunk (T/K)
#define NC     128     // CIN == COUT
#define NA     384     // CIN*KS
#define NZ     64
#define NH     32
#define NK     400
#define NCHUNK 1600    // B*K
#define MW     49152   // CIN*COUT*KS
#define XROWS  48002   // T + 2 zero prefix rows (causal taps)

typedef float f32x4 __attribute__((ext_vector_type(4)));
typedef __bf16 bf16x8 __attribute__((ext_vector_type(8)));

static __device__ __forceinline__ uint16_t f2bf(float f) {
    uint32_t x; __builtin_memcpy(&x, &f, 4);
    return (uint16_t)((x + 0x7fffu + ((x >> 16) & 1u)) >> 16);
}
static __device__ __forceinline__ uint32_t pk2(uint16_t lo, uint16_t hi) {
    return (uint32_t)lo | ((uint32_t)hi << 16);
}

// ---------------------------------------------------------------------------
// k0w: permute+convert w2 -> w2p bf16 [m'][32], m' = c*384 + a  (m = a*128+c)
//      and b2 -> b2p f32 [m'].
// ---------------------------------------------------------------------------
__global__ __launch_bounds__(256) void k0w(
    const float* __restrict__ w2, const float* __restrict__ b2,
    uint16_t* __restrict__ w2p, float* __restrict__ b2p) {
    int m = blockIdx.x * 256 + threadIdx.x;   // 0..49151
    int a = m >> 7, c = m & 127;
    int mp = c * NA + a;
    const float* src = w2 + (size_t)m * NH;
    uint16_t* dst = w2p + (size_t)mp * NH;
#pragma unroll
    for (int i = 0; i < NH; i += 8) {
        float4 v0 = *(const float4*)(src + i);
        float4 v1 = *(const float4*)(src + i + 4);
        uint4 o;
        o.x = pk2(f2bf(v0.x), f2bf(v0.y));
        o.y = pk2(f2bf(v0.z), f2bf(v0.w));
        o.z = pk2(f2bf(v1.x), f2bf(v1.y));
        o.w = pk2(f2bf(v1.z), f2bf(v1.w));
        *(uint4*)(dst + i) = o;
    }
    b2p[mp] = b2[m];
}

// ---------------------------------------------------------------------------
// k0x: transpose x[b][cin][t] f32 -> Xt[b][t+2][cin] bf16 (2 zero prefix rows)
// tile: 128 t x 64 cin per block
// ---------------------------------------------------------------------------
__global__ __launch_bounds__(256) void k0x(
    const float* __restrict__ x, uint16_t* __restrict__ Xt) {
    int t0 = blockIdx.x * 128, cin0 = blockIdx.y * 64, b = blockIdx.z;
    int tid = threadIdx.x;
    __shared__ __align__(16) uint16_t Lt[128][72];   // pad row to 72 (144B)
    const float* xb = x + ((size_t)b * NC + cin0) * TT + t0;
    int cg = (tid & 7) * 8;    // local cin base (0..56)
    int tq = (tid >> 3) * 4;   // local t base   (0..124)
    uint16_t vb[4][8];         // [t][cin]
#pragma unroll
    for (int i = 0; i < 8; ++i) {
        float4 v = *(const float4*)(xb + (size_t)(cg + i) * TT + tq);
        vb[0][i] = f2bf(v.x); vb[1][i] = f2bf(v.y);
        vb[2][i] = f2bf(v.z); vb[3][i] = f2bf(v.w);
    }
#pragma unroll
    for (int j = 0; j < 4; ++j) {
        uint4 o; __builtin_memcpy(&o, vb[j], 16);
        *(uint4*)&Lt[tq + j][cg] = o;
    }
    __syncthreads();
    uint16_t* XtB = Xt + (size_t)b * XROWS * NC;
#pragma unroll
    for (int r = 0; r < 4; ++r) {
        int s = r * 256 + tid;
        int t = s >> 3, cc = s & 7;
        uint4 o = *(uint4*)&Lt[t][cc * 8];
        *(uint4*)(XtB + (size_t)(t0 + t + 2) * NC + cin0 + cc * 8) = o;
    }
    if (blockIdx.x == 0 && blockIdx.y == 0 && tid < 32)
        *(uint4*)(XtB + tid * 8) = make_uint4(0, 0, 0, 0);  // zero rows -2,-1
}

// ---------------------------------------------------------------------------
// k1: 4 chunks per block (one per wave). All weights staged in LDS with
// conflict-free layouts; coalesced global loads.
// ---------------------------------------------------------------------------
__global__ __launch_bounds__(256) void k1_hidden(
    const float* __restrict__ z,
    const float* __restrict__ w1, const float* __restrict__ b1,
    const float* __restrict__ bw1, const float* __restrict__ bb1,
    const float* __restrict__ bw2, const float* __restrict__ bb2,
    uint16_t* __restrict__ Hb, float* __restrict__ biasws) {
    int tid = threadIdx.x, lane = tid & 63, w = tid >> 6;
    int chunk0 = blockIdx.x * 4;
    int b = chunk0 / NK;            // 400 % 4 == 0: all 4 chunks same b
    int k0 = chunk0 - b * NK;

    __shared__ float w1sT[64][33];   // [i][h] transposed, conflict-free reads
    __shared__ float bw1sT[64][33];
    __shared__ float bw2s[128][33];  // [c][j]
    __shared__ float zs[64][4];
    __shared__ float hbs[4][33];
    __shared__ float b1s[32], bb1s[32], bb2s[128];

    {   // stage w1, bw1 (transposed)
        int row = tid >> 3, c0 = (tid & 7) * 8;
        float4 a0 = *(const float4*)(w1 + row * NZ + c0);
        float4 a1 = *(const float4*)(w1 + row * NZ + c0 + 4);
        float4 c0v = *(const float4*)(bw1 + row * NZ + c0);
        float4 c1v = *(const float4*)(bw1 + row * NZ + c0 + 4);
        const float av[8] = {a0.x,a0.y,a0.z,a0.w,a1.x,a1.y,a1.z,a1.w};
        const float cv[8] = {c0v.x,c0v.y,c0v.z,c0v.w,c1v.x,c1v.y,c1v.z,c1v.w};
#pragma unroll
        for (int j = 0; j < 8; ++j) {
            w1sT[c0 + j][row]  = av[j];
            bw1sT[c0 + j][row] = cv[j];
        }
    }
    {   // stage bw2 [128][32]
        int r = tid >> 1, cb = (tid & 1) * 16;
        float4 v0 = *(const float4*)(bw2 + r * NH + cb);
        float4 v1 = *(const float4*)(bw2 + r * NH + cb + 4);
        float4 v2 = *(const float4*)(bw2 + r * NH + cb + 8);
        float4 v3 = *(const float4*)(bw2 + r * NH + cb + 12);
        const float vv[16] = {v0.x,v0.y,v0.z,v0.w,v1.x,v1.y,v1.z,v1.w,
                              v2.x,v2.y,v2.z,v2.w,v3.x,v3.y,v3.z,v3.w};
#pragma unroll
        for (int j = 0; j < 16; ++j) bw2s[r][cb + j] = vv[j];
    }
    if (tid < 64) {
        float4 zv = *(const float4*)(z + ((size_t)b * NZ + tid) * NK + k0);
        zs[tid][0] = zv.x; zs[tid][1] = zv.y; zs[tid][2] = zv.z; zs[tid][3] = zv.w;
    }
    if (tid < 32) { b1s[tid] = b1[tid]; bb1s[tid] = bb1[tid]; }
    if (tid >= 128 && tid < 256) bb2s[tid - 128] = bb2[tid - 128];
    __syncthreads();

    int chunk = chunk0 + w;
    if (lane < NH) {
        float s = b1s[lane];
#pragma unroll
        for (int i = 0; i < NZ; ++i) s = fmaf(w1sT[i][lane], zs[i][w], s);
        Hb[(size_t)chunk * NH + lane] = f2bf(fmaxf(s, 0.f));
    } else {
        int j = lane - NH;
        float s = bb1s[j];
#pragma unroll
        for (int i = 0; i < NZ; ++i) s = fmaf(bw1sT[i][j], zs[i][w], s);
        hbs[w][j] = fmaxf(s, 0.f);
    }

#pragma unroll
    for (int r = 0; r < 2; ++r) {
        int c = r * 64 + lane;
        float s = bb2s[c];
#pragma unroll
        for (int j = 0; j < NH; ++j) s = fmaf(bw2s[c][j], hbs[w][j], s);
        biasws[(size_t)chunk * NC + c] = s;
    }
}

// ---------------------------------------------------------------------------
// k2: MFMA weight materialization with LDS-staged coalesced stores.
// Wave computes 16 tiles (256 m' x 16 chunks), stashes bf16 results in
// LDS [16 chunk][264], then writes 256B-contiguous runs per chunk row.
// ---------------------------------------------------------------------------
__global__ __launch_bounds__(256) void k2_wgen(
    const uint16_t* __restrict__ w2p, const float* __restrict__ b2p,
    const uint16_t* __restrict__ Hb, uint16_t* __restrict__ Wt,
    int chunk0, int nchunk) {
    int tid = threadIdx.x, lane = tid & 63, w = tid >> 6;
    int quad = lane >> 4, li = lane & 15;
    __shared__ __align__(16) uint16_t St[4][16][264];  // pad 256->264: 2-way max

    int clocal = blockIdx.y * 16 + li;
    int cl = clocal < nchunk ? clocal : (nchunk - 1);
    bf16x8 bfrag = *(const bf16x8*)(Hb + (size_t)(chunk0 + cl) * NH + quad * 8);
    int mbase = blockIdx.x * 1024 + w * 256;

#pragma unroll
    for (int t = 0; t < 16; ++t) {
        int mb = mbase + t * 16;
        bf16x8 afrag = *(const bf16x8*)(w2p + (size_t)(mb + li) * NH + quad * 8);
        f32x4 acc = {0.f, 0.f, 0.f, 0.f};
        acc = __builtin_amdgcn_mfma_f32_16x16x32_bf16(afrag, bfrag, acc, 0, 0, 0);
        float4 bias = *(const float4*)(b2p + mb + quad * 4);
        uint16_t p[4] = { f2bf(acc[0] + bias.x), f2bf(acc[1] + bias.y),
                          f2bf(acc[2] + bias.z), f2bf(acc[3] + bias.w) };
        uint64_t pv; __builtin_memcpy(&pv, p, 8);
        *(uint64_t*)&St[w][li][t * 16 + quad * 4] = pv;   // D: row=quad*4+r, col(chunk)=li
    }
    // same-wave LDS readback (compiler inserts lgkmcnt wait; no barrier needed)
#pragma unroll
    for (int p = 0; p < 8; ++p) {
        int ch = (lane >> 4) + (p & 3) * 4;
        int part = lane & 15, mh = p >> 2;
        uint4 v = *(const uint4*)&St[w][ch][mh * 128 + part * 8];
        int cg = blockIdx.y * 16 + ch;
        if (cg < nchunk)
            *(uint4*)(Wt + (size_t)cg * MW + mbase + mh * 128 + part * 8) = v;
    }
}

// ---------------------------------------------------------------------------
// k3: per-chunk conv GEMM via MFMA. Block = chunk, 4 waves, each 64t x 64c.
// A/B staged with global_load_lds(16B) into [kc][row] layout
// (conflict-free ds_read_b128: bank group = 4*(lane&7)).
// ---------------------------------------------------------------------------
__global__ __launch_bounds__(256) void k3_conv(
    const uint16_t* __restrict__ Xt, const uint16_t* __restrict__ Wt,
    const float* __restrict__ biasws, float* __restrict__ out, int chunk0) {
    int cl = blockIdx.x, chunk = chunk0 + cl;
    int b = chunk / NK, k = chunk - b * NK;
    int kbase = k * TK;
    int tid = threadIdx.x, lane = tid & 63, w = tid >> 6;
    int quad = lane >> 4, li = lane & 15;
    int tblk = (w & 1) * 64, cblk = (w >> 1) * 64;

    __shared__ __align__(16) char smem[32768];
    char* As = smem;            // 8 kc x 128 t x 16B
    char* Ws = smem + 16384;    // 8 kc x 128 c x 16B
    const uint16_t* XtB = Xt + (size_t)b * XROWS * NC;
    const uint16_t* WtC = Wt + (size_t)cl * MW;

    f32x4 acc[4][4];
#pragma unroll
    for (int i = 0; i < 4; ++i)
#pragma unroll
        for (int j = 0; j < 4; ++j) acc[i][j] = (f32x4){0.f, 0.f, 0.f, 0.f};

#pragma unroll
    for (int dk = 0; dk < 6; ++dk) {
        int a0 = dk * 64, tap = a0 >> 7, cin0 = a0 & 127;
#pragma unroll
        for (int i = 0; i < 4; ++i) {
            int kc = 2 * w + (i >> 1), half = i & 1;
            int t = half * 64 + lane;
            const uint16_t* g = XtB + (size_t)(kbase + t - tap + 2) * NC + cin0 + kc * 8;
            __builtin_amdgcn_global_load_lds(
                (__attribute__((address_space(1))) void*)g,
                (__attribute__((address_space(3))) void*)(As + kc * 2048 + half * 1024),
                16, 0, 0);
        }
#pragma unroll
        for (int i = 0; i < 4; ++i) {
            int kc = 2 * w + (i >> 1), half = i & 1;
            int c = half * 64 + lane;
            const uint16_t* g = WtC + (size_t)c * NA + a0 + kc * 8;
            __builtin_amdgcn_global_load_lds(
                (__attribute__((address_space(1))) void*)g,
                (__attribute__((address_space(3))) void*)(Ws + kc * 2048 + half * 1024),
                16, 0, 0);
        }
        __syncthreads();
#pragma unroll
        for (int s = 0; s < 2; ++s) {
            bf16x8 af[4], bfr[4];
#pragma unroll
            for (int tt = 0; tt < 4; ++tt)
                af[tt] = *(const bf16x8*)(As + (s * 4 + quad) * 2048 + (tblk + tt * 16 + li) * 16);
#pragma unroll
            for (int ct = 0; ct < 4; ++ct)
                bfr[ct] = *(const bf16x8*)(Ws + (s * 4 + quad) * 2048 + (cblk + ct * 16 + li) * 16);
#pragma unroll
            for (int tt = 0; tt < 4; ++tt)
#pragma unroll
                for (int ct = 0; ct < 4; ++ct)
                    acc[tt][ct] = __builtin_amdgcn_mfma_f32_16x16x32_bf16(
                        af[tt], bfr[ct], acc[tt][ct], 0, 0, 0);
        }
        __syncthreads();
    }

    // epilogue: D col = c = lane&15 (+tile), row = t = quad*4+reg (+tile)
#pragma unroll
    for (int ct = 0; ct < 4; ++ct) {
        int c = cblk + ct * 16 + li;
        float bias = biasws[(size_t)chunk * NC + c];
        float* ob = out + ((size_t)b * NC + c) * TT + kbase;
#pragma unroll
        for (int tt = 0; tt < 4; ++tt) {
            int t0v = tblk + tt * 16 + quad * 4;
            if (t0v < TK) {
                f32x4 v = acc[tt][ct];
                *(float4*)(ob + t0v) = make_float4(v[0] + bias, v[1] + bias,
                                                   v[2] + bias, v[3] + bias);
            }
        }
    }
}

// ---------------------------------------------------------------------------
// launch
// ---------------------------------------------------------------------------
extern "C" void kernel_launch(void* const* d_in, const int* in_sizes, int n_in,
                              void* d_out, int out_size, void* d_ws, size_t ws_size,
                              hipStream_t stream) {
    const float* x   = (const float*)d_in[0];
    const float* z   = (const float*)d_in[1];
    const float* w1  = (const float*)d_in[2];
    const float* b1  = (const float*)d_in[3];
    const float* w2  = (const float*)d_in[4];
    const float* b2  = (const float*)d_in[5];
    const float* bw1 = (const float*)d_in[6];
    const float* bb1 = (const float*)d_in[7];
    const float* bw2 = (const float*)d_in[8];
    const float* bb2 = (const float*)d_in[9];
    float* out = (float*)d_out;

    // ws layout (all 256-aligned):
    char* ws = (char*)d_ws;
    uint16_t* Hb     = (uint16_t*)(ws);                 //   102,400 B
    float*    biasws = (float*)(ws + 102400);           //   819,200 B
    uint16_t* w2p    = (uint16_t*)(ws + 921600);        // 3,145,728 B
    float*    b2p    = (float*)(ws + 4067328);          //   196,608 B
    uint16_t* Xt     = (uint16_t*)(ws + 4263936);       // 49,158,144 B (incl. tail pad)
    const size_t wt_off = 53422080;
    uint16_t* Wt     = (uint16_t*)(ws + wt_off);        // slice buffer

    // L3 blocking: keep the Wt slice resident in Infinity Cache between
    // k2 (producer) and k3 (consumer). 800 chunks -> 78.6 MB slice.
    size_t avail = (ws_size > wt_off) ? (ws_size - wt_off) : 0;
    int batch = (int)(avail / ((size_t)MW * 2));
    if (batch > 800) batch = 800;
    if (batch < 1) batch = 1;

    k0w<<<MW / 256, 256, 0, stream>>>(w2, b2, w2p, b2p);
    k0x<<<dim3(TT / 128, 2, 4), 256, 0, stream>>>(x, Xt);
    k1_hidden<<<NCHUNK / 4, 256, 0, stream>>>(z, w1, b1, bw1, bb1, bw2, bb2, Hb, biasws);

    for (int c0 = 0; c0 < NCHUNK; c0 += batch) {
        int nc = NCHUNK - c0;
        if (nc > batch) nc = batch;
        dim3 g2(MW / 1024, (nc + 15) / 16, 1);
        k2_wgen<<<g2, 256, 0, stream>>>(w2p, b2p, Hb, Wt, c0, nc);
        k3_conv<<<nc, 256, 0, stream>>>(Xt, Wt, biasws, out, c0);
    }
}